// Round 3
// baseline (1262.855 us; speedup 1.0000x reference)
//
#include <hip/hip_runtime.h>

namespace {
constexpr int UNITS = 2048;
constexpr int D_IN  = 96;
constexpr int BATCH = 64;
constexpr int T     = 512;
constexpr int NNZ   = 960;   // D_IN * C_IN
constexpr int C_REC = 10;
constexpr int CHUNK = 128;   // x timesteps staged in LDS per refill
constexpr int NT    = 1024;  // threads per block; one block per batch element

// LDS byte-offset arena
constexpr int HA = 0;          // h ping   (2048 f32 = 8 KB)
constexpr int HB = 8192;       // h pong   (8 KB)
constexpr int IA = 16384;      // input_part ping (8 KB)
constexpr int IB = 24576;      // input_part pong (8 KB)
constexpr int XO = 32768;      // x chunk  (128*96 f32 = 48 KB)
constexpr int LDS_BYTES = XO + CHUNK * D_IN * 4;   // 80 KB total
}

// native 2-float vector: __builtin_nontemporal_store requires a real vector
// type, not HIP's float2 class
typedef float f32x2 __attribute__((ext_vector_type(2)));

// Barrier WITHOUT vmcnt drain: __syncthreads() emits s_waitcnt vmcnt(0) which
// would stall every step on the streaming out-stores. We only need LDS
// visibility -> lgkmcnt(0) + s_barrier.
__device__ __forceinline__ void bar_lds() {
  asm volatile("s_waitcnt lgkmcnt(0)\n\ts_barrier" ::: "memory");
}

// tanh(x) = 1 - 2/(exp(2x)+1); exact at +-inf, abs err ~1e-7 vs 2e-2 threshold
__device__ __forceinline__ float fast_tanh(float x) {
  float e = __expf(2.0f * x);
  return 1.0f - __fdividef(2.0f, e + 1.0f);
}

// One timestep as a macro (NOT a function): the recurrent index/weight arrays
// must never be address-taken, so SROA can promote them to VGPRs. Round-1
// version passed them as const int* into a helper -> scratch spill (VGPR=36,
// ~40 scratch buffer_loads per thread per step).
// HC = h current, HN = h next, IR = input_part consumed this step (read then
// re-zeroed), IW = input_part being built for step t+1.
#define STEP(HC, HN, IR, IW, SLOT_NEXT, DO_SCATTER, TSTEP)                     \
  {                                                                            \
    if ((DO_SCATTER) && tid < NNZ) {                                           \
      float xv = *(const float*)(smem + XO + (SLOT_NEXT) * (D_IN * 4) + krb);  \
      atomicAdd((float*)(smem + (IW) + kcb), xv * kv);                         \
    }                                                                          \
    f32x2 in2 = *(f32x2*)(smem + (IR) + tid * 8);                              \
    *(f32x2*)(smem + (IR) + tid * 8) = (f32x2){0.f, 0.f};                      \
    float s0 = in2.x + bias2.x;                                                \
    float s1 = in2.y + bias2.y;                                                \
    _Pragma("unroll")                                                          \
    for (int c = 0; c < C_REC; ++c) {                                          \
      s0 += *(const float*)(smem + (HC) + idxb0[c]) * w0[c];                   \
      s1 += *(const float*)(smem + (HC) + idxb1[c]) * w1[c];                   \
    }                                                                          \
    f32x2 hh = {fast_tanh(s0), fast_tanh(s1)};                                 \
    *(f32x2*)(smem + (HN) + tid * 8) = hh;                                     \
    __builtin_nontemporal_store(hh, outp + (size_t)(TSTEP) * (UNITS / 2));     \
    bar_lds();                                                                 \
  }

// __launch_bounds__(1024, 4): 4 waves/EU min = exactly 1 block/CU (LDS=80KB
// forces that anyway) -> 128-VGPR budget so the 40 hoisted idx/weight values
// stay in registers instead of spilling to scratch.
__global__ __launch_bounds__(NT, 4) void reservoir_kernel(
    const float* __restrict__ inputs, const float* __restrict__ state0,
    const float* __restrict__ kvals,  const float* __restrict__ rvals,
    const float* __restrict__ bias,   const int* __restrict__ krows,
    const int* __restrict__ kcols,    const int* __restrict__ ridx,
    float* __restrict__ out)
{
  __shared__ __align__(16) char smem[LDS_BYTES];
  const int tid = threadIdx.x;
  const int b   = blockIdx.x;
  const int u0  = tid * 2;          // each thread owns units u0, u0+1

  // zero input_part ping+pong (16 KB): one float4 store per thread
  *(float4*)(smem + IA + tid * 16) = make_float4(0.f, 0.f, 0.f, 0.f);
  // stage h_0
  *(f32x2*)(smem + HA + tid * 8) = *(const f32x2*)(state0 + b * UNITS + u0);

  // hoist recurrent weights into VGPRs: 20 byte-offsets + 20 vals per thread
  int   idxb0[C_REC], idxb1[C_REC];
  float w0[C_REC], w1[C_REC];
#pragma unroll
  for (int c = 0; c < C_REC; ++c) {
    idxb0[c] = ridx[u0 * C_REC + c] * 4;
    idxb1[c] = ridx[u0 * C_REC + C_REC + c] * 4;
    w0[c]    = rvals[u0 * C_REC + c];
    w1[c]    = rvals[u0 * C_REC + C_REC + c];
  }
  const f32x2 bias2 = *(const f32x2*)(bias + u0);

  // input-kernel COO entry for this thread (960 entries, threads 960..1023 idle)
  int krb = 0, kcb = 0; float kv = 0.f;
  if (tid < NNZ) {
    krb = krows[tid] * 4;
    kcb = kcols[tid] * 4;
    kv  = kvals[tid];
  }

  const float* xin  = inputs + (size_t)b * (T * D_IN);
  f32x2*       outp = (f32x2*)out + (size_t)b * (T * (UNITS / 2)) + tid;

  __syncthreads();   // prologue: full barrier once is fine

  for (int tb = 0; tb < T; tb += CHUNK) {
    // bulk-refill x chunk (48 KB); all readers of the previous chunk are at
    // least one phase-barrier behind us
#pragma unroll
    for (int k = 0; k < 3; ++k) {
      float4 v = *(const float4*)(xin + tb * D_IN + (tid + k * NT) * 4);
      *(float4*)(smem + XO + (tid + k * NT) * 16) = v;
    }
    bar_lds();
    // prime input_part for the first step of this chunk (slot 0 -> ping buf;
    // ping was left zeroed by the previous chunk's last even phase / prologue)
    if (tid < NNZ) {
      float xv = *(const float*)(smem + XO + krb);
      atomicAdd((float*)(smem + IA + kcb), xv * kv);
    }
    bar_lds();
#pragma unroll 1
    for (int ts = 0; ts < CHUNK; ts += 2) {
      STEP(HA, HB, IA, IB, ts + 1, true,              tb + ts);
      STEP(HB, HA, IB, IA, ts + 2, (ts + 2) < CHUNK,  tb + ts + 1);
    }
  }
}

extern "C" void kernel_launch(void* const* d_in, const int* in_sizes, int n_in,
                              void* d_out, int out_size, void* d_ws, size_t ws_size,
                              hipStream_t stream) {
  const float* inputs = (const float*)d_in[0];
  const float* state0 = (const float*)d_in[1];
  const float* kvals  = (const float*)d_in[2];
  const float* rvals  = (const float*)d_in[3];
  const float* bias   = (const float*)d_in[4];
  const int*   krows  = (const int*)d_in[5];
  const int*   kcols  = (const int*)d_in[6];
  const int*   ridx   = (const int*)d_in[7];

  reservoir_kernel<<<dim3(BATCH), dim3(NT), 0, stream>>>(
      inputs, state0, kvals, rvals, bias, krows, kcols, ridx, (float*)d_out);
}

// Round 4
// 1256.266 us; speedup vs baseline: 1.0052x; 1.0052x over previous
//
#include <hip/hip_runtime.h>

namespace {
constexpr int UNITS = 2048;
constexpr int D_IN  = 96;
constexpr int BATCH = 64;
constexpr int T     = 512;
constexpr int NNZ   = 960;   // D_IN * C_IN
constexpr int C_REC = 10;
constexpr int CHUNK = 128;   // x timesteps staged in LDS per refill
constexpr int NT    = 1024;  // threads per block; one block per batch element

// LDS byte-offset arena
constexpr int HA = 0;          // h ping   (2048 f32 = 8 KB)
constexpr int HB = 8192;       // h pong   (8 KB)
constexpr int IA = 16384;      // input_part ping (8 KB)
constexpr int IB = 24576;      // input_part pong (8 KB)
constexpr int XO = 32768;      // x chunk  (128*96 f32 = 48 KB)
constexpr int LDS_BYTES = XO + CHUNK * D_IN * 4;   // 80 KB total
}

// native 2-float vector: __builtin_nontemporal_store requires a real vector
// type, not HIP's float2 class
typedef float f32x2 __attribute__((ext_vector_type(2)));

// Barrier WITHOUT vmcnt drain: __syncthreads() emits s_waitcnt vmcnt(0) which
// would stall every step on the streaming out-stores. We only need LDS
// visibility -> lgkmcnt(0) + s_barrier.
__device__ __forceinline__ void bar_lds() {
  asm volatile("s_waitcnt lgkmcnt(0)\n\ts_barrier" ::: "memory");
}

// tanh(x) = 1 - 2/(exp(2x)+1); exact at +-inf, abs err ~1e-7 vs 2e-2 threshold
__device__ __forceinline__ float fast_tanh(float x) {
  float e = __expf(2.0f * x);
  return 1.0f - __fdividef(2.0f, e + 1.0f);
}

// Recurrent weights as 40 NAMED SCALARS, never arrays. Rounds 1-2 used
// int idx[10] arrays: SROA runs before loop-unroll, sees runtime index c,
// leaves the allocas in scratch -> 40 scratch buffer_loads per thread per
// step on the gather dependence chain (VGPR_Count stuck at 36, dur ~1262us).
// Named scalars are SSA values from the frontend; no alloca ever exists.
#define REC_DECL(n)                                          \
  const int   ia##n = ridx[u0 * C_REC + n] * 4;              \
  const int   ib##n = ridx[u0 * C_REC + C_REC + n] * 4;      \
  const float wa##n = rvals[u0 * C_REC + n];                 \
  const float wb##n = rvals[u0 * C_REC + C_REC + n];

#define GATHER(HC, n)                                        \
  s0 += *(const float*)(smem + (HC) + ia##n) * wa##n;        \
  s1 += *(const float*)(smem + (HC) + ib##n) * wb##n;

// One timestep. HC = h current, HN = h next, IR = input_part consumed this
// step (read then re-zeroed), IW = input_part being built for step t+1.
#define STEP(HC, HN, IR, IW, SLOT_NEXT, DO_SCATTER, TSTEP)                     \
  {                                                                            \
    if ((DO_SCATTER) && tid < NNZ) {                                           \
      float xv = *(const float*)(smem + XO + (SLOT_NEXT) * (D_IN * 4) + krb);  \
      atomicAdd((float*)(smem + (IW) + kcb), xv * kv);                         \
    }                                                                          \
    f32x2 in2 = *(f32x2*)(smem + (IR) + tid * 8);                              \
    *(f32x2*)(smem + (IR) + tid * 8) = (f32x2){0.f, 0.f};                      \
    float s0 = in2.x + bias2.x;                                                \
    float s1 = in2.y + bias2.y;                                                \
    GATHER(HC, 0) GATHER(HC, 1) GATHER(HC, 2) GATHER(HC, 3) GATHER(HC, 4)      \
    GATHER(HC, 5) GATHER(HC, 6) GATHER(HC, 7) GATHER(HC, 8) GATHER(HC, 9)      \
    f32x2 hh = {fast_tanh(s0), fast_tanh(s1)};                                 \
    *(f32x2*)(smem + (HN) + tid * 8) = hh;                                     \
    __builtin_nontemporal_store(hh, outp + (size_t)(TSTEP) * (UNITS / 2));     \
    bar_lds();                                                                 \
  }

// __launch_bounds__(1024, 4): 4 waves/EU min = exactly 1 block/CU (LDS=80KB
// forces that anyway) -> 128-VGPR budget for the ~60 live scalars.
__global__ __launch_bounds__(NT, 4) void reservoir_kernel(
    const float* __restrict__ inputs, const float* __restrict__ state0,
    const float* __restrict__ kvals,  const float* __restrict__ rvals,
    const float* __restrict__ bias,   const int* __restrict__ krows,
    const int* __restrict__ kcols,    const int* __restrict__ ridx,
    float* __restrict__ out)
{
  __shared__ __align__(16) char smem[LDS_BYTES];
  const int tid = threadIdx.x;
  const int b   = blockIdx.x;
  const int u0  = tid * 2;          // each thread owns units u0, u0+1

  // zero input_part ping+pong (16 KB): one float4 store per thread
  *(float4*)(smem + IA + tid * 16) = make_float4(0.f, 0.f, 0.f, 0.f);
  // stage h_0
  *(f32x2*)(smem + HA + tid * 8) = *(const f32x2*)(state0 + b * UNITS + u0);

  // 40 named scalars -> VGPRs (see REC_DECL comment)
  REC_DECL(0) REC_DECL(1) REC_DECL(2) REC_DECL(3) REC_DECL(4)
  REC_DECL(5) REC_DECL(6) REC_DECL(7) REC_DECL(8) REC_DECL(9)

  const f32x2 bias2 = *(const f32x2*)(bias + u0);

  // input-kernel COO entry for this thread (960 entries, threads 960..1023 idle)
  int krb = 0, kcb = 0; float kv = 0.f;
  if (tid < NNZ) {
    krb = krows[tid] * 4;
    kcb = kcols[tid] * 4;
    kv  = kvals[tid];
  }

  const float* xin  = inputs + (size_t)b * (T * D_IN);
  f32x2*       outp = (f32x2*)out + (size_t)b * (T * (UNITS / 2)) + tid;

  __syncthreads();   // prologue: full barrier once is fine

  for (int tb = 0; tb < T; tb += CHUNK) {
    // bulk-refill x chunk (48 KB); all readers of the previous chunk are at
    // least one phase-barrier behind us
#pragma unroll
    for (int k = 0; k < 3; ++k) {
      float4 v = *(const float4*)(xin + tb * D_IN + (tid + k * NT) * 4);
      *(float4*)(smem + XO + (tid + k * NT) * 16) = v;
    }
    bar_lds();
    // prime input_part for the first step of this chunk (slot 0 -> ping buf;
    // ping was left zeroed by the previous chunk's last even phase / prologue)
    if (tid < NNZ) {
      float xv = *(const float*)(smem + XO + krb);
      atomicAdd((float*)(smem + IA + kcb), xv * kv);
    }
    bar_lds();
#pragma unroll 1
    for (int ts = 0; ts < CHUNK; ts += 2) {
      STEP(HA, HB, IA, IB, ts + 1, true,              tb + ts);
      STEP(HB, HA, IB, IA, ts + 2, (ts + 2) < CHUNK,  tb + ts + 1);
    }
  }
}

extern "C" void kernel_launch(void* const* d_in, const int* in_sizes, int n_in,
                              void* d_out, int out_size, void* d_ws, size_t ws_size,
                              hipStream_t stream) {
  const float* inputs = (const float*)d_in[0];
  const float* state0 = (const float*)d_in[1];
  const float* kvals  = (const float*)d_in[2];
  const float* rvals  = (const float*)d_in[3];
  const float* bias   = (const float*)d_in[4];
  const int*   krows  = (const int*)d_in[5];
  const int*   kcols  = (const int*)d_in[6];
  const int*   ridx   = (const int*)d_in[7];

  reservoir_kernel<<<dim3(BATCH), dim3(NT), 0, stream>>>(
      inputs, state0, kvals, rvals, bias, krows, kcols, ridx, (float*)d_out);
}